// Round 9
// baseline (259.457 us; speedup 1.0000x reference)
//
#include <hip/hip_runtime.h>
#include <stdint.h>

// Problem constants
#define NLAYERS 32
#define DSIZE   1024
#define OSIZE   1024
#define BATCH   32
#define SEQ     256

// ws layout (ints): [0]=ntiles; [16..272)=perm; [512 + 4*t ..]=tile{layer, rank_base, nranks, pad}
#define WS_PERM  16
#define WS_TILE  512
#define MAX_TILES 88   // sum ceil(cnt/4) <= 64 + 24 = 88
#define NSPLIT   16    // o-dim tiles of 64

typedef __attribute__((ext_vector_type(8)))  short short8;
typedef __attribute__((ext_vector_type(16))) float f32x16;

#define LDSTRIDE 72   // shorts per LDS row (64 + 8 pad; 144 B = 16B-aligned rows)
#define BK 64

// Barrier waiting ONLY on LDS ops (lgkmcnt): global prefetch loads stay in
// flight across it; they are waited per-register at the pk2 consume point.
static __device__ __forceinline__ void lds_barrier() {
    asm volatile("s_waitcnt lgkmcnt(0)\n\ts_barrier" ::: "memory");
}

__global__ void prep_kernel(const int* __restrict__ layer_idx, int* __restrict__ wsi) {
    __shared__ int cnt[NLAYERS];
    __shared__ int start_[NLAYERS];
    __shared__ int cursor[NLAYERS];
    const int t = threadIdx.x;
    if (t < NLAYERS) cnt[t] = 0;
    __syncthreads();
    int l = 0;
    if (t < SEQ) { l = layer_idx[t]; atomicAdd(&cnt[l], 1); }
    __syncthreads();
    if (t == 0) {
        int acc = 0;
        for (int i = 0; i < NLAYERS; ++i) { start_[i] = acc; cursor[i] = acc; acc += cnt[i]; }
    }
    __syncthreads();
    if (t < SEQ) {
        int r = atomicAdd(&cursor[l], 1);
        wsi[WS_PERM + r] = t;           // perm[rank] = s  (order within layer irrelevant)
    }
    if (t == 0) {
        int nt = 0;
        for (int i = 0; i < NLAYERS; ++i) {
            const int c = cnt[i];
            for (int j = 0; j < c; j += 4) {
                wsi[WS_TILE + nt*4 + 0] = i;
                wsi[WS_TILE + nt*4 + 1] = start_[i] + j;
                wsi[WS_TILE + nt*4 + 2] = (c - j < 4) ? (c - j) : 4;
                ++nt;
            }
        }
        wsi[0] = nt;   // 64..88
    }
}

// round-to-nearest fp32->bf16 pair pack: low16 = bf16(a), high16 = bf16(b)
static __device__ __forceinline__ unsigned pk2(float a, float b) {
    unsigned ua = __builtin_bit_cast(unsigned, a) + 0x8000u;
    unsigned ub = __builtin_bit_cast(unsigned, b) + 0x8000u;
    return __builtin_amdgcn_perm(ub, ua, 0x07060302u);  // {ua[2],ua[3],ub[2],ub[3]}
}

// Tile: 128 m-rows (4 ranks x 32 batch) x 64 o-cols, BK=64, **8 waves**.
// Wave wv: rank ro = wv>>1 (rows 32*ro..32*ro+32), n-half nh = wv&1
// (cols nh*32..nh*32+32) -> acc = one 32x32 = 16 AGPR.
// R8 cycle accounting: >50% of elapsed = un-overlapped load-latency stall at
// ~2.6 resident blocks/CU. R9 halves per-thread staging (ra[4]+rb[2]=24 VGPR,
// ~55 arch + 16 AGPR ~ 70 unified <= 73 cap) -> launch_bounds(512,7):
// 24 waves/CU nominal (75%), >=2 independent barrier domains per SIMD.
//
// Grid 1408 blocks. XCD mapping (fid%8 = XCD under round-robin dispatch):
// xcd owns chunk run [xcd*nt/8,(xcd+1)*nt/8) x 16 ntiles -> FETCH ~100MB
// (R6-measured ~compulsory), bank conflicts 0 at LDSTRIDE=72.
__global__ __launch_bounds__(512, 7) void gemm_kernel(
        const float* __restrict__ x, const float* __restrict__ wgt,
        const int* __restrict__ wsi, float* __restrict__ out) {
    const int ntiles = wsi[0];
    const int xcd = blockIdx.x & 7;
    const int idx = blockIdx.x >> 3;                    // 0..175
    const int g_lo = (xcd * ntiles) >> 3;
    const int g_hi = ((xcd + 1) * ntiles) >> 3;
    const int nblk = (g_hi - g_lo) << 4;                // chunks-in-run * 16 ntiles
    if (idx >= nblk) return;
    const int mt    = g_lo + (idx >> 4);                // chunk id
    const int ntile = idx & 15;                         // o block of 64
    const int layer     = wsi[WS_TILE + mt*4 + 0];
    const int rank_base = wsi[WS_TILE + mt*4 + 1];
    const int nranks    = wsi[WS_TILE + mt*4 + 2];

    __shared__ __align__(16) short ldsA[128 * LDSTRIDE];
    __shared__ __align__(16) short ldsB[64 * LDSTRIDE];

    const int t     = threadIdx.x;                      // 0..511
    // ---- coalesced staging: 16 lanes x 16B = 256B segments; rbase = row 0..31
    const int c4    = (t & 15) * 4;   // float (== bf16-short) column within 64-wide k-slab
    const int rbase = t >> 4;         // 0..31; pass p covers row = rbase + 32*p

    // A rows: row = rbase + 32p (p=0..3) -> rank = p, batch = rbase
    int sv[4];
    #pragma unroll
    for (int j = 0; j < 4; ++j)
        sv[j] = (j < nranks) ? wsi[WS_PERM + rank_base + j] : 0;

    const float* abase = x + (((size_t)(rbase * SEQ)) << 10) + c4;
    // B rows: orow = ntile*64 + rbase + 32p (p=0..1)
    const float* bptr = wgt + (((size_t)((layer << 10) + ntile * 64 + rbase)) << 10) + c4;

    float4 ra[4], rb[2];
    auto load_step = [&](int kk) {
        #pragma unroll
        for (int p = 0; p < 4; ++p) {
            if (p < nranks) ra[p] = *(const float4*)(abase + ((size_t)sv[p] << 10) + kk);
            else            ra[p] = make_float4(0.f, 0.f, 0.f, 0.f);
        }
        #pragma unroll
        for (int p = 0; p < 2; ++p)
            rb[p] = *(const float4*)(bptr + ((size_t)p << 15) + kk);   // +p*32 rows
    };

    // compute-side mapping: 8 waves -> (rank ro, n-half nh)
    const int lane = t & 63;
    const int wv   = t >> 6;          // 0..7
    const int ro   = wv >> 1;         // rank 0..3
    const int nh   = wv & 1;          // n half 0..1
    const int l31  = lane & 31;
    const int lh   = lane >> 5;

    f32x16 acc;
    #pragma unroll
    for (int r = 0; r < 16; ++r) acc[r] = 0.f;

    const short* pA0 = &ldsA[(ro * 32 + l31) * LDSTRIDE + lh * 8];
    const short* pB0 = &ldsB[(nh * 32 + l31) * LDSTRIDE + lh * 8];

    load_step(0);
    #pragma unroll 1
    for (int kk = 0; kk < DSIZE; kk += BK) {
        lds_barrier();     // previous compute done reading LDS (lgkm only)
        #pragma unroll
        for (int p = 0; p < 4; ++p) {
            const int row = rbase + 32 * p;
            uint2 va;
            va.x = pk2(ra[p].x, ra[p].y);
            va.y = pk2(ra[p].z, ra[p].w);
            *(uint2*)&ldsA[row * LDSTRIDE + c4] = va;
        }
        #pragma unroll
        for (int p = 0; p < 2; ++p) {
            const int row = rbase + 32 * p;
            uint2 vb;
            vb.x = pk2(rb[p].x, rb[p].y);
            vb.y = pk2(rb[p].z, rb[p].w);
            *(uint2*)&ldsB[row * LDSTRIDE + c4] = vb;
        }
        // issue next-slab loads NOW (registers just freed by pk2); they stay
        // in flight across the lgkm-barrier and the MFMA phase.
        if (kk + BK < DSIZE) load_step(kk + BK);
        lds_barrier();     // LDS writes visible; vmem prefetch NOT drained
        #pragma unroll
        for (int sub = 0; sub < 4; ++sub) {       // 4 x (K=16) sub-steps
            short8 a0 = *(const short8*)(pA0 + sub*16);
            short8 b0 = *(const short8*)(pB0 + sub*16);
            acc = __builtin_amdgcn_mfma_f32_32x32x16_bf16(a0, b0, acc, 0, 0, 0);
        }
    }

    // epilogue: C/D layout col = lane&31, row = (reg&3) + 8*(reg>>2) + 4*(lane>>5)
    if (ro < nranks) {
        const int s = wsi[WS_PERM + rank_base + ro];
        const int ocol = ntile * 64 + nh * 32 + l31;
        #pragma unroll
        for (int r = 0; r < 16; ++r) {
            const int brow = (r & 3) + 8 * (r >> 2) + 4 * lh;  // = batch b
            out[(((size_t)(brow * SEQ + s)) << 10) + ocol] = acc[r];
        }
    }
}

extern "C" void kernel_launch(void* const* d_in, const int* in_sizes, int n_in,
                              void* d_out, int out_size, void* d_ws, size_t ws_size,
                              hipStream_t stream) {
    const float* x         = (const float*)d_in[0];
    const int*   layer_idx = (const int*)  d_in[1];
    const float* weight    = (const float*)d_in[2];
    float* out = (float*)d_out;
    int*   wsi = (int*)d_ws;

    prep_kernel<<<1, 256, 0, stream>>>(layer_idx, wsi);
    gemm_kernel<<<MAX_TILES * NSPLIT, 512, 0, stream>>>(x, weight, wsi, out);
}